// Round 2
// 373.351 us; speedup vs baseline: 1.1220x; 1.1220x over previous
//
#include <hip/hip_runtime.h>
#include <stdint.h>

// Problem constants (from reference): B=8, L=4096, D=1024, S=255
constexpr int kB = 8;
constexpr int kL = 4096;
constexpr int kD = 1024;
constexpr int kS = 255;
constexpr int kM = kB * kL;   // 32768 rows of A / out
constexpr int kK = 2 * kD;    // 2048 reduction dim
constexpr int kN = kD;        // 1024 output features

typedef __bf16 bf16x8 __attribute__((ext_vector_type(8)));
typedef float  f32x4  __attribute__((ext_vector_type(4)));

// ---- workspace layout (bytes), unchanged from prior rounds ----
constexpr size_t WS_WORDS = 0;                                   // 67,108,864 B bf16
constexpr size_t WS_SENTS = WS_WORDS + (size_t)kM * kD * 2;      // 67,108,864
constexpr size_t WS_W     = WS_SENTS + (size_t)kB * kS * kD * 2; // +4,177,920
constexpr size_t WS_ZP    = WS_W + (size_t)kN * kK * 2;          // +4,194,304
constexpr size_t WS_NEED  = WS_ZP + 3072;                        // zero page 3 KiB

// fp32 pair -> packed bf16x2, round-half-up (matches validated accuracy)
__device__ __forceinline__ uint32_t pk_bf16x2(float a, float b) {
    uint32_t ua = __float_as_uint(a) + 0x8000u;
    uint32_t ub = __float_as_uint(b) + 0x8000u;
    return __builtin_amdgcn_perm(ub, ua, 0x07060302u);
}

// async global->LDS 16B per lane: dest = wave-uniform base + lane*16
__device__ __forceinline__ void async16(const void* g, void* l) {
    __builtin_amdgcn_global_load_lds(
        (const __attribute__((address_space(1))) uint32_t*)g,
        (__attribute__((address_space(3))) uint32_t*)l, 16, 0, 0);
}

#define WAITVM(n)  asm volatile("s_waitcnt vmcnt(" #n ")" ::: "memory")
#define WAITLGKM0  asm volatile("s_waitcnt lgkmcnt(0)" ::: "memory")

__device__ __forceinline__ void blockbar() {
    asm volatile("" ::: "memory");
    __builtin_amdgcn_s_barrier();
    asm volatile("" ::: "memory");
}

// ===================== prepass v2: fp32 -> bf16, grid-stride =================
// 32 B read + 16 B write per thread-iteration, 2048 blocks.
__global__ __launch_bounds__(256)
void cvt_prepass2(const float4* __restrict__ words, const float4* __restrict__ sents,
                  const float4* __restrict__ W,
                  uint4* __restrict__ wordsB, uint4* __restrict__ sentsB,
                  uint4* __restrict__ WB, uint32_t* __restrict__ zp)
{
    constexpr size_t NW8 = (size_t)kM * kD / 8;       // 4,194,304
    constexpr size_t NS8 = (size_t)kB * kS * kD / 8;  //   261,120
    constexpr size_t NB8 = (size_t)kN * kK / 8;       //   262,144
    constexpr size_t NT8 = NW8 + NS8 + NB8;
    if (blockIdx.x == 0) {                            // zero page for invalid rows
        for (int t = threadIdx.x; t < 768; t += 256) zp[t] = 0u;
    }
    const size_t stride = (size_t)gridDim.x * blockDim.x;
    for (size_t i = (size_t)blockIdx.x * blockDim.x + threadIdx.x; i < NT8; i += stride) {
        const float4* src; uint4* dst; size_t j;
        if (i < NW8)            { src = words; dst = wordsB; j = i; }
        else if (i < NW8 + NS8) { src = sents; dst = sentsB; j = i - NW8; }
        else                    { src = W;     dst = WB;     j = i - NW8 - NS8; }
        float4 a  = src[2 * j];
        float4 b2 = src[2 * j + 1];
        uint4 o;
        o.x = pk_bf16x2(a.x,  a.y);
        o.y = pk_bf16x2(a.z,  a.w);
        o.z = pk_bf16x2(b2.x, b2.y);
        o.w = pk_bf16x2(b2.z, b2.w);
        dst[j] = o;
    }
}

// ===================== main GEMM v2.1: 256x256, BK=32, triple-buffered ======
// C[m,n] = relu( sum_k A[m,k]*W[n,k] + bias[n] )
// Schedule: counted vmcnt(4) (never 0 in steady state), raw s_barrier,
// setprio around MFMA clusters, 2 phases per K-step.
// v2.1 race fix: s_waitcnt lgkmcnt(0) BEFORE bar_top each iteration. The
// compiler may sink the pure-register MFMA cluster (and its lgkm wait) past
// the asm barrier (rule #18 class), leaving phase-B ds_reads of buf[(t-1)%3]
// in flight when the iter-t DMA overwrites that buffer. Pinning lgkmcnt(0)
// before the barrier anchors read-completion to the barrier itself.
// LDS swizzle: phys_chunk = chunk ^ (row&3) ^ ((row>>2)&3) applied via
// pre-swizzled per-lane GLOBAL source (global_load_lds dest stays linear).
__global__ __launch_bounds__(512, 2)
void wsib_gemm_v2(const uint8_t* __restrict__ wordsB,   // [32768][1024] bf16
                  const uint8_t* __restrict__ sentsB,   // [8*255][1024] bf16
                  const uint8_t* __restrict__ WB,       // [1024][2048]  bf16
                  const float*   __restrict__ bias,
                  const int*     __restrict__ smap,
                  const uint8_t* __restrict__ zp,
                  float* __restrict__ out)
{
    __shared__ uint8_t lds[3][2][16384];   // [buf][A=0/B=1][256 rows][64 B] = 96 KiB

    const int tid  = threadIdx.x;
    const int w    = tid >> 6;           // wave 0..7
    const int lane = tid & 63;
    const int nT = blockIdx.x;           // 0..3
    const int mT = blockIdx.y;           // 0..127

    // wave tile: 2M x 4N decomposition, each wave owns 128x64 of C
    const int wm = (w >> 2) * 128;
    const int wn = (w & 3) * 64;
    const int fr = lane & 15, quad = lane >> 4;

    // bias for epilogue — load BEFORE any staging so the vmcnt stream in the
    // main loop contains only global_load_lds events (compiler-sunk loads are
    // still safe: vmcnt retires in order, tile t's DMAs are always oldest).
    float bv[4];
    #pragma unroll
    for (int ni = 0; ni < 4; ++ni) bv[ni] = bias[nT * 256 + wn + ni * 16 + fr];

    // ---- staging source pointers (per lane, pre-swizzled) ----
    const int lrow = lane >> 2;
    const int cph  = lane & 3;
    const int lc   = cph ^ (lrow & 3) ^ ((lrow >> 2) & 3);
    const int rloc0 = w * 32 + lrow;          // A/B rows covered by this thread
    const int rloc1 = rloc0 + 16;
    const int gA0 = mT * 256 + rloc0, gA1 = mT * 256 + rloc1;
    const uint8_t* aw0 = wordsB + (size_t)gA0 * 2048 + lc * 16;
    const uint8_t* aw1 = wordsB + (size_t)gA1 * 2048 + lc * 16;
    const int bIdx = gA0 >> 12;               // tile never crosses batch (4096%256==0)
    const int s0 = smap[gA0], s1 = smap[gA1];
    const uint8_t* as0 = (s0 >= 0) ? sentsB + (size_t)(bIdx * kS + s0) * 2048 + lc * 16
                                   : zp + lc * 16;
    const uint8_t* as1 = (s1 >= 0) ? sentsB + (size_t)(bIdx * kS + s1) * 2048 + lc * 16
                                   : zp + lc * 16;
    const uint8_t* wb0 = WB + (size_t)(nT * 256 + rloc0) * 4096 + lc * 16;
    const uint8_t* wb1 = WB + (size_t)(nT * 256 + rloc1) * 4096 + lc * 16;

    // fragment read offsets (swizzled); XOR reduces to a per-thread constant.
    const int pc   = quad ^ (fr & 3) ^ ((fr >> 2) & 3);
    const int offA = (wm + fr) * 64 + pc * 16;   // + mi*1024
    const int offB = (wn + fr) * 64 + pc * 16;   // + ni*1024

    f32x4 acc[8][4];
    #pragma unroll
    for (int i = 0; i < 8; ++i)
        #pragma unroll
        for (int j = 0; j < 4; ++j) acc[i][j] = (f32x4){0.f, 0.f, 0.f, 0.f};

    auto srcA0 = [&](int t) { return (t < 32) ? aw0 + (t << 6) : as0 + ((t - 32) << 6); };
    auto srcA1 = [&](int t) { return (t < 32) ? aw1 + (t << 6) : as1 + ((t - 32) << 6); };

    // ---- prologue: stage K-steps 0 and 1 into buf0, buf1 (8 loads/wave) ----
    {
        uint8_t* A0 = lds[0][0]; uint8_t* B0 = lds[0][1];
        async16(srcA0(0), A0 + w * 2048);
        async16(srcA1(0), A0 + w * 2048 + 1024);
        async16(wb0,      B0 + w * 2048);
        async16(wb1,      B0 + w * 2048 + 1024);
        uint8_t* A1 = lds[1][0]; uint8_t* B1 = lds[1][1];
        async16(srcA0(1), A1 + w * 2048);
        async16(srcA1(1), A1 + w * 2048 + 1024);
        async16(wb0 + 64, B1 + w * 2048);
        async16(wb1 + 64, B1 + w * 2048 + 1024);
    }

    // ---- main loop: 64 K-steps of 32 ----
    int bufR = 0;   // = t % 3
    #pragma unroll 1
    for (int t = 0; t < 64; ++t) {
        uint8_t* ldsAr = lds[bufR][0];
        uint8_t* ldsBr = lds[bufR][1];
        const int bufS = (bufR == 0) ? 2 : bufR - 1;   // (t+2)%3
        uint8_t* ldsAs = lds[bufS][0];
        uint8_t* ldsBs = lds[bufS][1];
        const int tS = t + 2;

        // RACE FIX: drain this wave's outstanding ds_reads (prev iteration's
        // phase-B frags of buf[(t-1)%3]) before arriving at the barrier —
        // after the barrier, other waves DMA into exactly that buffer.
        WAITLGKM0;
        // tile t's 4 loads complete; tile t+1's 4 stay in flight (counted, not 0)
        if (t < 63) { WAITVM(4); } else { WAITVM(0); }
        blockbar();

        // ---- phase A: B-frags + A-frags mi0..3, stage next A half ----
        bf16x8 bf[4];
        #pragma unroll
        for (int ni = 0; ni < 4; ++ni)
            bf[ni] = *(const bf16x8*)(ldsBr + offB + ni * 1024);
        bf16x8 af[4];
        #pragma unroll
        for (int mi = 0; mi < 4; ++mi)
            af[mi] = *(const bf16x8*)(ldsAr + offA + mi * 1024);
        if (tS < 64) {
            async16(srcA0(tS), ldsAs + w * 2048);
            async16(srcA1(tS), ldsAs + w * 2048 + 1024);
        }
        blockbar();
        __builtin_amdgcn_s_setprio(1);
        #pragma unroll
        for (int mi = 0; mi < 4; ++mi)
            #pragma unroll
            for (int ni = 0; ni < 4; ++ni)
                acc[mi][ni] = __builtin_amdgcn_mfma_f32_16x16x32_bf16(
                    af[mi], bf[ni], acc[mi][ni], 0, 0, 0);
        __builtin_amdgcn_s_setprio(0);

        // ---- phase B: A-frags mi4..7, stage next B half ----
        bf16x8 ag[4];
        #pragma unroll
        for (int mi = 0; mi < 4; ++mi)
            ag[mi] = *(const bf16x8*)(ldsAr + offA + (mi + 4) * 1024);
        if (tS < 64) {
            async16(wb0 + (tS << 6), ldsBs + w * 2048);
            async16(wb1 + (tS << 6), ldsBs + w * 2048 + 1024);
        }
        blockbar();
        __builtin_amdgcn_s_setprio(1);
        #pragma unroll
        for (int mi = 0; mi < 4; ++mi)
            #pragma unroll
            for (int ni = 0; ni < 4; ++ni)
                acc[mi + 4][ni] = __builtin_amdgcn_mfma_f32_16x16x32_bf16(
                    ag[mi], bf[ni], acc[mi + 4][ni], 0, 0, 0);
        __builtin_amdgcn_s_setprio(0);

        bufR = (bufR == 2) ? 0 : bufR + 1;
    }

    // ---- epilogue: bias + relu, fp32 store ----
    // C/D layout (verified): col = lane&15, row = quad*4 + r
    const int rowBase = mT * 256 + wm + quad * 4;
    const int colBase = nT * 256 + wn + fr;
    #pragma unroll
    for (int mi = 0; mi < 8; ++mi) {
        #pragma unroll
        for (int ni = 0; ni < 4; ++ni) {
            const int col = colBase + ni * 16;
            #pragma unroll
            for (int r = 0; r < 4; ++r) {
                const int row = rowBase + mi * 16 + r;
                out[(size_t)row * kN + col] = fmaxf(acc[mi][ni][r] + bv[ni], 0.f);
            }
        }
    }
}

// ===================== fallback (R2 kernel, no-workspace path) ==============
#define TILE_M 128
#define TILE_N 128
#define TILE_K 32
#define LDS_STRIDE 20
__global__ __launch_bounds__(256)
void wsib_gemm_fb(const float* __restrict__ words, const float* __restrict__ sents,
                  const float* __restrict__ W, const float* __restrict__ bias,
                  const int* __restrict__ smap, float* __restrict__ out)
{
    __shared__ uint32_t Asm[TILE_M * LDS_STRIDE];
    __shared__ uint32_t Bsm[TILE_N * LDS_STRIDE];
    const int tid = threadIdx.x, nT = blockIdx.x, mT = blockIdx.y;
    const int sRow = tid >> 1, half = tid & 1;
    const int mRow = mT * TILE_M + sRow, bIdx = mRow >> 12;
    const float* wsrc = words + (size_t)mRow * kD + half * 16;
    const int sidx = smap[mRow];
    const float* ssrc = (sidx >= 0) ? sents + ((size_t)bIdx * kS + sidx) * kD + half * 16 : nullptr;
    const float* bsrc = W + (size_t)(nT * TILE_N + sRow) * kK + half * 16;
    uint32_t* adst = &Asm[sRow * LDS_STRIDE + half * 8];
    uint32_t* bdst = &Bsm[sRow * LDS_STRIDE + half * 8];
    const int lane = tid & 63, wv = tid >> 6;
    const int wm = (wv & 1) * 64, wn = (wv >> 1) * 64;
    const int fr = lane & 15, quad = lane >> 4;
    f32x4 acc[4][4];
    #pragma unroll
    for (int i = 0; i < 4; ++i)
        #pragma unroll
        for (int j = 0; j < 4; ++j) acc[i][j] = (f32x4){0.f, 0.f, 0.f, 0.f};
    float4 ra[4], rb[4];
    {
        const float4* pa = (const float4*)wsrc; const float4* pb = (const float4*)bsrc;
        #pragma unroll
        for (int i = 0; i < 4; ++i) { ra[i] = pa[i]; rb[i] = pb[i]; }
    }
    for (int k0 = 0; k0 < kK; k0 += TILE_K) {
        uint32_t pa[8], pb[8];
        #pragma unroll
        for (int i = 0; i < 4; ++i) {
            pa[2*i] = pk_bf16x2(ra[i].x, ra[i].y); pa[2*i+1] = pk_bf16x2(ra[i].z, ra[i].w);
            pb[2*i] = pk_bf16x2(rb[i].x, rb[i].y); pb[2*i+1] = pk_bf16x2(rb[i].z, rb[i].w);
        }
        __syncthreads();
        ((uint4*)adst)[0] = make_uint4(pa[0], pa[1], pa[2], pa[3]);
        ((uint4*)adst)[1] = make_uint4(pa[4], pa[5], pa[6], pa[7]);
        ((uint4*)bdst)[0] = make_uint4(pb[0], pb[1], pb[2], pb[3]);
        ((uint4*)bdst)[1] = make_uint4(pb[4], pb[5], pb[6], pb[7]);
        __syncthreads();
        const int k1 = k0 + TILE_K;
        if (k1 < kK) {
            const float* asrc = (k1 < kD) ? (wsrc + k1) : (ssrc ? (ssrc + (k1 - kD)) : nullptr);
            if (asrc) { const float4* p = (const float4*)asrc;
                #pragma unroll
                for (int i = 0; i < 4; ++i) ra[i] = p[i];
            } else {
                #pragma unroll
                for (int i = 0; i < 4; ++i) ra[i] = make_float4(0.f, 0.f, 0.f, 0.f);
            }
            const float4* p = (const float4*)(bsrc + k1);
            #pragma unroll
            for (int i = 0; i < 4; ++i) rb[i] = p[i];
        }
        bf16x8 af[4], bfv[4];
        #pragma unroll
        for (int mi = 0; mi < 4; ++mi)
            af[mi] = *(const bf16x8*)&Asm[(wm + mi * 16 + fr) * LDS_STRIDE + quad * 4];
        #pragma unroll
        for (int ni = 0; ni < 4; ++ni)
            bfv[ni] = *(const bf16x8*)&Bsm[(wn + ni * 16 + fr) * LDS_STRIDE + quad * 4];
        #pragma unroll
        for (int mi = 0; mi < 4; ++mi)
            #pragma unroll
            for (int ni = 0; ni < 4; ++ni)
                acc[mi][ni] = __builtin_amdgcn_mfma_f32_16x16x32_bf16(af[mi], bfv[ni], acc[mi][ni], 0, 0, 0);
    }
    const int rowBase = mT * TILE_M + wm, colBase = nT * TILE_N + wn;
    float bv[4];
    #pragma unroll
    for (int ni = 0; ni < 4; ++ni) bv[ni] = bias[colBase + ni * 16 + fr];
    #pragma unroll
    for (int mi = 0; mi < 4; ++mi)
        #pragma unroll
        for (int ni = 0; ni < 4; ++ni) {
            const int col = colBase + ni * 16 + fr;
            #pragma unroll
            for (int r = 0; r < 4; ++r) {
                const int row = rowBase + mi * 16 + quad * 4 + r;
                out[(size_t)row * kN + col] = fmaxf(acc[mi][ni][r] + bv[ni], 0.f);
            }
        }
}

extern "C" void kernel_launch(void* const* d_in, const int* in_sizes, int n_in,
                              void* d_out, int out_size, void* d_ws, size_t ws_size,
                              hipStream_t stream) {
    const float* words = (const float*)d_in[0];   // [8, 4096, 1024] f32
    const float* sents = (const float*)d_in[1];   // [8, 255, 1024]  f32
    const float* W     = (const float*)d_in[2];   // [1024, 2048]    f32
    const float* bias  = (const float*)d_in[3];   // [1024]          f32
    const int*   smap  = (const int*)d_in[4];     // [8, 4096]       i32
    float* out = (float*)d_out;                   // [8, 4096, 1024] f32

    if (ws_size >= WS_NEED) {
        uint8_t* ws = (uint8_t*)d_ws;
        uint4* wordsB = (uint4*)(ws + WS_WORDS);
        uint4* sentsB = (uint4*)(ws + WS_SENTS);
        uint4* WB     = (uint4*)(ws + WS_W);
        uint32_t* zp  = (uint32_t*)(ws + WS_ZP);
        cvt_prepass2<<<2048, 256, 0, stream>>>(
            (const float4*)words, (const float4*)sents, (const float4*)W,
            wordsB, sentsB, WB, zp);
        dim3 grid(kN / 256, kM / 256);            // (4, 128)
        wsib_gemm_v2<<<grid, 512, 0, stream>>>(
            (const uint8_t*)wordsB, (const uint8_t*)sentsB, (const uint8_t*)WB,
            bias, smap, (const uint8_t*)zp, out);
    } else {
        dim3 grid(kN / TILE_N, kM / TILE_M);
        wsib_gemm_fb<<<grid, 256, 0, stream>>>(words, sents, W, bias, smap, out);
    }
}